// Round 10
// baseline (807.355 us; speedup 1.0000x reference)
//
#include <hip/hip_runtime.h>
#include <stdint.h>

// VQ-VAE nearest-codebook index: N=32768 queries, D=64, K=8192 codes.
// R10: single fused kernel, grid 1024 co-resident (launch_bounds(256,4):
// VGPR cap 128 >> natural 84 of the R9 16x16 phase-1 -> no spill; LDS 33.5KB*4
// =134<=160KB). Rationale: harness charges ~20-25us per dispatch (R7 fused
// residue 25us vs 104-139us for 5-kernel rounds); R7's fusion only lost because
// grid 512 starved the 32x32 phase-1 -- the 16x16 kernel runs at grid 1024.
//   P0 prep: codebook hi/lo bf16 split + norms          (blocks 0..255)
//   P1 mfma: R9-proven 16x16x32 bf16x3 + s2 tracking    (1024 = 256 qblk x 4 part)
//   P2 merge 4 partitions, flag gap<EPS                 (blocks 0..127)
//   P3 exact fp32, k-tiled shared codebook              (64 ks x 16 egrp)
//   P4 write back flagged                               (blocks 0..127)
// Barrier/cnt counters zeroed via hipMemsetAsync (capture-safe, R7-proven).
// Fallback: R9-proven 5-kernel path, then fp32 path, if ws too small.

#define N_TOTAL 32768
#define K_CODES 8192
#define EPS_GAP 0.015f
#define NPART   4
#define GRID_F  1024
#define CBP     129

typedef __attribute__((ext_vector_type(4))) float  floatx4;
typedef __attribute__((ext_vector_type(8))) __bf16 bf16x8;

// ---- workspace layout (bytes) ----
#define O_C2    0u          // 8192 f32
#define O_CBSW  32768u      // [512 tile16][hi/lo][h][g][code16] = 2 MB
#define O_PS1   2129920u    // 4*32768 f32
#define O_PS2   2654208u    // 4*32768 f32
#define O_PI1   3178496u    // 4*32768 i32
#define O_CNT   3702784u    // cnt @ +0, 4 barrier counters @ +16..+31
#define O_LIST  3703040u    // 32768 int
#define O_SLOT  3834112u    // 32768 u64
#define WS_NEED 4096256u

#if defined(__has_builtin)
#if __has_builtin(__builtin_amdgcn_fmed3f)
#define MED3(a, b, c) __builtin_amdgcn_fmed3f((a), (b), (c))
#endif
#endif
#ifndef MED3
#define MED3(a, b, c) fminf((c), fmaxf((a), (b)))
#endif

__device__ __forceinline__ unsigned int fkey(float s) {
    unsigned int u = __float_as_uint(s);
    return (u & 0x80000000u) ? ~u : (u | 0x80000000u);
}

__device__ __forceinline__ void load_lds16(const void* g, void* l) {
    __builtin_amdgcn_global_load_lds(
        (const __attribute__((address_space(1))) unsigned int*)g,
        (__attribute__((address_space(3))) unsigned int*)l, 16, 0, 0);
}

// single-use device-scope grid barrier; counter pre-zeroed by hipMemsetAsync.
__device__ __forceinline__ void grid_bar(int* bar) {
    __syncthreads();
    if (threadIdx.x == 0) {
        __threadfence();
        atomicAdd(bar, 1);
        while (__hip_atomic_load(bar, __ATOMIC_RELAXED, __HIP_MEMORY_SCOPE_AGENT) < GRID_F)
            __builtin_amdgcn_s_sleep(1);
        __threadfence();
    }
    __syncthreads();
}

__global__ __launch_bounds__(256, 4) void vq_fused2(
    const float4* __restrict__ lat, const float4* __restrict__ cb,
    int* __restrict__ out, float* __restrict__ c2, uint4* __restrict__ cbSw,
    float* __restrict__ pS1, float* __restrict__ pS2, int* __restrict__ pI1,
    int* __restrict__ cntbar, int* __restrict__ list,
    unsigned long long* __restrict__ slot) {
    __shared__ __align__(16) char shRaw[33664];   // max(Bs 32KB, CbT 33024+c2s 512)
    uint4* Bs  = (uint4*)shRaw;
    const int tid = threadIdx.x;
    const int bid = blockIdx.x;
    int* cnt  = cntbar;
    int* bars = cntbar + 4;

    // ---------------- P0: codebook split + norms (blocks 0..255) ----------------
    if (bid < 256) {
        const int t = bid * 256 + tid;             // 65536 items = code*8 + sub
        const int code = t >> 3, sub = t & 7, h = sub >> 2, g = sub & 3;
        float4 f0 = cb[(size_t)code * 16 + h * 8 + g * 2];
        float4 f1 = cb[(size_t)code * 16 + h * 8 + g * 2 + 1];
        float x[8] = {f0.x, f0.y, f0.z, f0.w, f1.x, f1.y, f1.z, f1.w};
        bf16x8 hv, lv;
        float ss = 0.f;
#pragma unroll
        for (int i = 0; i < 8; ++i) {
            float v  = x[i];
            __bf16 hb = (__bf16)v;                  // RNE
            hv[i] = hb;
            lv[i] = (__bf16)(v - (float)hb);
            ss += v * v;
        }
        const int base = (code >> 4) * 256 + h * 64 + g * 16 + (code & 15);
        cbSw[base]       = __builtin_bit_cast(uint4, hv);
        cbSw[base + 128] = __builtin_bit_cast(uint4, lv);
        ss += __shfl_xor(ss, 1);
        ss += __shfl_xor(ss, 2);
        ss += __shfl_xor(ss, 4);
        if (sub == 0) c2[code] = ss;
    }
    grid_bar(&bars[0]);

    // ---------------- P1: 16x16x32 bf16x3 MFMA (R9-proven math) ----------------
    {
        const int wr = tid >> 6, lane = tid & 63;
        const int lm = lane & 15, lg = lane >> 4;
        const int qblk = bid >> 2, part = bid & 3;
        const int qBaseW = qblk * 128 + wr * 32;

        bf16x8 aH[2][2], aL[2][2];
#pragma unroll
        for (int qt = 0; qt < 2; ++qt) {
            const int q = qBaseW + qt * 16 + lm;
#pragma unroll
            for (int h = 0; h < 2; ++h) {
                float4 v0 = lat[(size_t)q * 16 + h * 8 + lg * 2];
                float4 v1 = lat[(size_t)q * 16 + h * 8 + lg * 2 + 1];
                float x[8] = {v0.x, v0.y, v0.z, v0.w, v1.x, v1.y, v1.z, v1.w};
#pragma unroll
                for (int j = 0; j < 8; ++j) {
                    float v  = x[j];
                    __bf16 hb = (__bf16)v;
                    aH[qt][h][j] = hb;
                    aL[qt][h][j] = (__bf16)(v - (float)hb);
                }
            }
        }

        float s1[2][4], s2[2][4]; int i1[2][4];
#pragma unroll
        for (int qt = 0; qt < 2; ++qt)
#pragma unroll
            for (int r = 0; r < 4; ++r) { s1[qt][r] = 3e38f; s2[qt][r] = 3e38f; i1[qt][r] = 0; }

        const int kBase = part * 2048;
        const size_t uBase = (size_t)part * 32768;

        for (int stage = 0; stage < 16; ++stage) {
            __syncthreads();
#pragma unroll
            for (int i = 0; i < 8; ++i)
                load_lds16(&cbSw[uBase + stage * 2048 + wr * 64 + 256 * i + lane],
                           &Bs[wr * 64 + 256 * i]);
            __syncthreads();

#pragma unroll
            for (int t = 0; t < 8; ++t) {
                const int b = t * 256;
                bf16x8 bH0 = __builtin_bit_cast(bf16x8, Bs[b + lane]);
                bf16x8 bH1 = __builtin_bit_cast(bf16x8, Bs[b + 64 + lane]);
                bf16x8 bL0 = __builtin_bit_cast(bf16x8, Bs[b + 128 + lane]);
                bf16x8 bL1 = __builtin_bit_cast(bf16x8, Bs[b + 192 + lane]);
                const int col = kBase + stage * 128 + t * 16 + lm;
                const float cc = c2[col];
#pragma unroll
                for (int qt = 0; qt < 2; ++qt) {
                    floatx4 acc = {0.f, 0.f, 0.f, 0.f};
                    acc = __builtin_amdgcn_mfma_f32_16x16x32_bf16(aH[qt][0], bH0, acc, 0, 0, 0);
                    acc = __builtin_amdgcn_mfma_f32_16x16x32_bf16(aH[qt][1], bH1, acc, 0, 0, 0);
                    acc = __builtin_amdgcn_mfma_f32_16x16x32_bf16(aL[qt][0], bH0, acc, 0, 0, 0);
                    acc = __builtin_amdgcn_mfma_f32_16x16x32_bf16(aL[qt][1], bH1, acc, 0, 0, 0);
                    acc = __builtin_amdgcn_mfma_f32_16x16x32_bf16(aH[qt][0], bL0, acc, 0, 0, 0);
                    acc = __builtin_amdgcn_mfma_f32_16x16x32_bf16(aH[qt][1], bL1, acc, 0, 0, 0);
#pragma unroll
                    for (int r = 0; r < 4; ++r) {
                        float s = fmaf(-2.f, acc[r], cc);
                        s2[qt][r] = MED3(s, s1[qt][r], s2[qt][r]);
                        bool lt = s < s1[qt][r];
                        i1[qt][r] = lt ? col : i1[qt][r];
                        s1[qt][r] = lt ? s : s1[qt][r];
                    }
                }
            }
        }

#pragma unroll
        for (int mask = 1; mask <= 8; mask <<= 1) {
#pragma unroll
            for (int qt = 0; qt < 2; ++qt)
#pragma unroll
                for (int r = 0; r < 4; ++r) {
                    float o1 = __shfl_xor(s1[qt][r], mask);
                    float o2 = __shfl_xor(s2[qt][r], mask);
                    int   oi = __shfl_xor(i1[qt][r], mask);
                    float n2 = fminf(fminf(s2[qt][r], o2), fmaxf(s1[qt][r], o1));
                    bool take = (o1 < s1[qt][r]) || (o1 == s1[qt][r] && oi < i1[qt][r]);
                    s1[qt][r] = take ? o1 : s1[qt][r];
                    i1[qt][r] = take ? oi : i1[qt][r];
                    s2[qt][r] = n2;
                }
        }

        if (lm == 0) {
            const int o0 = part * N_TOTAL;
#pragma unroll
            for (int qt = 0; qt < 2; ++qt)
#pragma unroll
                for (int r = 0; r < 4; ++r) {
                    int q = qBaseW + qt * 16 + lg * 4 + r;   // C/D row = lg*4+r
                    pS1[o0 + q] = s1[qt][r];
                    pS2[o0 + q] = s2[qt][r];
                    pI1[o0 + q] = i1[qt][r];
                }
        }
    }
    grid_bar(&bars[1]);

    // ---------------- P2: merge 4 partitions + flag (blocks 0..127) ----------------
    if (bid < 128) {
        int q = bid * 256 + tid;
        float g1 = 3e38f, g2 = 3e38f;
        int   gi = 0x7FFFFFFF;
#pragma unroll
        for (int p = 0; p < NPART; ++p) {
            float s1p = pS1[p * N_TOTAL + q];
            float s2p = pS2[p * N_TOTAL + q];
            int   i1p = pI1[p * N_TOTAL + q];
            bool take = (s1p < g1) || (s1p == g1 && i1p < gi);
            g2 = fminf(g2, fminf(s2p, take ? g1 : s1p));
            if (take) { g1 = s1p; gi = i1p; }
        }
        out[q] = gi;
        if (g2 - g1 < EPS_GAP) {
            int e = atomicAdd(cnt, 1);
            list[e] = q;
            slot[e] = 0xFFFFFFFFFFFFFFFFull;
        }
    }
    grid_bar(&bars[2]);

    // ---------------- P3: exact fp32, k-tiled shared codebook ----------------
    {
        const int n = *cnt;
        if (n > 0) {
            float* CbT = (float*)shRaw;                 // 64*CBP floats
            float* c2s = (float*)(shRaw + 64 * CBP * 4);
            const int ks = bid & 63, egrp = bid >> 6;   // 64 slices x 16 groups
            for (int i = tid; i < 2048; i += 256) {
                int code = i >> 4, d4 = i & 15;
                float4 v = cb[(size_t)(ks * 128 + code) * 16 + d4];
                CbT[(d4 * 4 + 0) * CBP + code] = v.x;
                CbT[(d4 * 4 + 1) * CBP + code] = v.y;
                CbT[(d4 * 4 + 2) * CBP + code] = v.z;
                CbT[(d4 * 4 + 3) * CBP + code] = v.w;
            }
            if (tid < 128) c2s[tid] = c2[ks * 128 + tid];
            __syncthreads();

            const int code = tid >> 1, dh = tid & 1;
            for (int e = egrp; e < n; e += 16) {
                const int qq = list[e];
                const float4* qp = lat + (size_t)qq * 16 + dh * 8;
                float dot = 0.f;
#pragma unroll
                for (int j = 0; j < 8; ++j) {
                    float4 qv = qp[j];
                    dot += qv.x * CbT[(dh * 32 + j * 4 + 0) * CBP + code]
                         + qv.y * CbT[(dh * 32 + j * 4 + 1) * CBP + code]
                         + qv.z * CbT[(dh * 32 + j * 4 + 2) * CBP + code]
                         + qv.w * CbT[(dh * 32 + j * 4 + 3) * CBP + code];
                }
                dot += __shfl_xor(dot, 1);
                float s = c2s[code] - 2.f * dot;
                unsigned long long p =
                    ((unsigned long long)fkey(s) << 32) | (unsigned)(ks * 128 + code);
#pragma unroll
                for (int mask = 1; mask <= 32; mask <<= 1) {
                    unsigned long long o = __shfl_xor(p, mask);
                    p = o < p ? o : p;
                }
                if ((tid & 63) == 0) atomicMin(&slot[e], p);
            }
        }
    }
    grid_bar(&bars[3]);

    // ---------------- P4: write back flagged (blocks 0..127) ----------------
    if (bid < 128) {
        int t = bid * 256 + tid;
        if (t < *cnt) out[list[t]] = (int)(slot[t] & 0xFFFFFFFFull);
    }
}

// ================= fallback 1: R9-proven 5-kernel path =================
__global__ __launch_bounds__(256) void vq_prep16(
    const float4* __restrict__ cb, uint4* __restrict__ cbSw,
    float* __restrict__ c2, int* __restrict__ cnt) {
    const int t = blockIdx.x * 256 + threadIdx.x;
    if (t == 0) *cnt = 0;
    const int code = t >> 3, sub = t & 7, h = sub >> 2, g = sub & 3;
    float4 f0 = cb[(size_t)code * 16 + h * 8 + g * 2];
    float4 f1 = cb[(size_t)code * 16 + h * 8 + g * 2 + 1];
    float x[8] = {f0.x, f0.y, f0.z, f0.w, f1.x, f1.y, f1.z, f1.w};
    bf16x8 hv, lv;
    float ss = 0.f;
#pragma unroll
    for (int i = 0; i < 8; ++i) {
        float v  = x[i];
        __bf16 hb = (__bf16)v;
        hv[i] = hb;
        lv[i] = (__bf16)(v - (float)hb);
        ss += v * v;
    }
    const int base = (code >> 4) * 256 + h * 64 + g * 16 + (code & 15);
    cbSw[base]       = __builtin_bit_cast(uint4, hv);
    cbSw[base + 128] = __builtin_bit_cast(uint4, lv);
    ss += __shfl_xor(ss, 1);
    ss += __shfl_xor(ss, 2);
    ss += __shfl_xor(ss, 4);
    if (sub == 0) c2[code] = ss;
}

__global__ __launch_bounds__(256, 3) void vq_mfma16(
    const float4* __restrict__ lat, const uint4* __restrict__ cbSw,
    const float* __restrict__ c2,
    float* __restrict__ pS1, float* __restrict__ pS2, int* __restrict__ pI1) {
    __shared__ uint4 Bs[2048];
    const int tid = threadIdx.x;
    const int wr = tid >> 6, lane = tid & 63;
    const int lm = lane & 15, lg = lane >> 4;
    const int qBaseW = blockIdx.x * 128 + wr * 32;
    bf16x8 aH[2][2], aL[2][2];
#pragma unroll
    for (int qt = 0; qt < 2; ++qt) {
        const int q = qBaseW + qt * 16 + lm;
#pragma unroll
        for (int h = 0; h < 2; ++h) {
            float4 v0 = lat[(size_t)q * 16 + h * 8 + lg * 2];
            float4 v1 = lat[(size_t)q * 16 + h * 8 + lg * 2 + 1];
            float x[8] = {v0.x, v0.y, v0.z, v0.w, v1.x, v1.y, v1.z, v1.w};
#pragma unroll
            for (int j = 0; j < 8; ++j) {
                float v  = x[j];
                __bf16 hb = (__bf16)v;
                aH[qt][h][j] = hb;
                aL[qt][h][j] = (__bf16)(v - (float)hb);
            }
        }
    }
    float s1[2][4], s2[2][4]; int i1[2][4];
#pragma unroll
    for (int qt = 0; qt < 2; ++qt)
#pragma unroll
        for (int r = 0; r < 4; ++r) { s1[qt][r] = 3e38f; s2[qt][r] = 3e38f; i1[qt][r] = 0; }
    const int kBase = blockIdx.y * 2048;
    const size_t uBase = (size_t)blockIdx.y * 32768;
    for (int stage = 0; stage < 16; ++stage) {
        __syncthreads();
#pragma unroll
        for (int i = 0; i < 8; ++i)
            load_lds16(&cbSw[uBase + stage * 2048 + wr * 64 + 256 * i + lane],
                       &Bs[wr * 64 + 256 * i]);
        __syncthreads();
#pragma unroll
        for (int t = 0; t < 8; ++t) {
            const int b = t * 256;
            bf16x8 bH0 = __builtin_bit_cast(bf16x8, Bs[b + lane]);
            bf16x8 bH1 = __builtin_bit_cast(bf16x8, Bs[b + 64 + lane]);
            bf16x8 bL0 = __builtin_bit_cast(bf16x8, Bs[b + 128 + lane]);
            bf16x8 bL1 = __builtin_bit_cast(bf16x8, Bs[b + 192 + lane]);
            const int col = kBase + stage * 128 + t * 16 + lm;
            const float cc = c2[col];
#pragma unroll
            for (int qt = 0; qt < 2; ++qt) {
                floatx4 acc = {0.f, 0.f, 0.f, 0.f};
                acc = __builtin_amdgcn_mfma_f32_16x16x32_bf16(aH[qt][0], bH0, acc, 0, 0, 0);
                acc = __builtin_amdgcn_mfma_f32_16x16x32_bf16(aH[qt][1], bH1, acc, 0, 0, 0);
                acc = __builtin_amdgcn_mfma_f32_16x16x32_bf16(aL[qt][0], bH0, acc, 0, 0, 0);
                acc = __builtin_amdgcn_mfma_f32_16x16x32_bf16(aL[qt][1], bH1, acc, 0, 0, 0);
                acc = __builtin_amdgcn_mfma_f32_16x16x32_bf16(aH[qt][0], bL0, acc, 0, 0, 0);
                acc = __builtin_amdgcn_mfma_f32_16x16x32_bf16(aH[qt][1], bL1, acc, 0, 0, 0);
#pragma unroll
                for (int r = 0; r < 4; ++r) {
                    float s = fmaf(-2.f, acc[r], cc);
                    s2[qt][r] = MED3(s, s1[qt][r], s2[qt][r]);
                    bool lt = s < s1[qt][r];
                    i1[qt][r] = lt ? col : i1[qt][r];
                    s1[qt][r] = lt ? s : s1[qt][r];
                }
            }
        }
    }
#pragma unroll
    for (int mask = 1; mask <= 8; mask <<= 1) {
#pragma unroll
        for (int qt = 0; qt < 2; ++qt)
#pragma unroll
            for (int r = 0; r < 4; ++r) {
                float o1 = __shfl_xor(s1[qt][r], mask);
                float o2 = __shfl_xor(s2[qt][r], mask);
                int   oi = __shfl_xor(i1[qt][r], mask);
                float n2 = fminf(fminf(s2[qt][r], o2), fmaxf(s1[qt][r], o1));
                bool take = (o1 < s1[qt][r]) || (o1 == s1[qt][r] && oi < i1[qt][r]);
                s1[qt][r] = take ? o1 : s1[qt][r];
                i1[qt][r] = take ? oi : i1[qt][r];
                s2[qt][r] = n2;
            }
    }
    if (lm == 0) {
        const int o0 = blockIdx.y * N_TOTAL;
#pragma unroll
        for (int qt = 0; qt < 2; ++qt)
#pragma unroll
            for (int r = 0; r < 4; ++r) {
                int q = qBaseW + qt * 16 + lg * 4 + r;
                pS1[o0 + q] = s1[qt][r];
                pS2[o0 + q] = s2[qt][r];
                pI1[o0 + q] = i1[qt][r];
            }
    }
}

__global__ void vq_merge4(const float* __restrict__ pS1, const float* __restrict__ pS2,
                          const int* __restrict__ pI1, int* __restrict__ out,
                          int* __restrict__ cnt, int* __restrict__ list,
                          unsigned long long* __restrict__ slot) {
    int q = blockIdx.x * 256 + threadIdx.x;
    float g1 = 3e38f, g2 = 3e38f;
    int   gi = 0x7FFFFFFF;
#pragma unroll
    for (int p = 0; p < NPART; ++p) {
        float s1p = pS1[p * N_TOTAL + q];
        float s2p = pS2[p * N_TOTAL + q];
        int   i1p = pI1[p * N_TOTAL + q];
        bool take = (s1p < g1) || (s1p == g1 && i1p < gi);
        g2 = fminf(g2, fminf(s2p, take ? g1 : s1p));
        if (take) { g1 = s1p; gi = i1p; }
    }
    out[q] = gi;
    if (g2 - g1 < EPS_GAP) {
        int e = atomicAdd(cnt, 1);
        list[e] = q;
        slot[e] = 0xFFFFFFFFFFFFFFFFull;
    }
}

__global__ __launch_bounds__(256) void vq_exact3(
    const float4* __restrict__ lat, const float4* __restrict__ cb,
    const float* __restrict__ c2, const int* __restrict__ cnt,
    const int* __restrict__ list, unsigned long long* __restrict__ slot) {
    __shared__ float CbT[64 * CBP];
    __shared__ float c2s[128];
    const int n = *cnt;
    if (n == 0) return;
    const int ks = blockIdx.x;
    const int egrp = blockIdx.y;
    const int tid = threadIdx.x;
    for (int i = tid; i < 2048; i += 256) {
        int code = i >> 4, d4 = i & 15;
        float4 v = cb[(size_t)(ks * 128 + code) * 16 + d4];
        CbT[(d4 * 4 + 0) * CBP + code] = v.x;
        CbT[(d4 * 4 + 1) * CBP + code] = v.y;
        CbT[(d4 * 4 + 2) * CBP + code] = v.z;
        CbT[(d4 * 4 + 3) * CBP + code] = v.w;
    }
    if (tid < 128) c2s[tid] = c2[ks * 128 + tid];
    __syncthreads();
    const int code = tid >> 1, dh = tid & 1;
    for (int e = egrp; e < n; e += 8) {
        const int qq = list[e];
        const float4* qp = lat + (size_t)qq * 16 + dh * 8;
        float dot = 0.f;
#pragma unroll
        for (int j = 0; j < 8; ++j) {
            float4 qv = qp[j];
            dot += qv.x * CbT[(dh * 32 + j * 4 + 0) * CBP + code]
                 + qv.y * CbT[(dh * 32 + j * 4 + 1) * CBP + code]
                 + qv.z * CbT[(dh * 32 + j * 4 + 2) * CBP + code]
                 + qv.w * CbT[(dh * 32 + j * 4 + 3) * CBP + code];
        }
        dot += __shfl_xor(dot, 1);
        float s = c2s[code] - 2.f * dot;
        unsigned long long p =
            ((unsigned long long)fkey(s) << 32) | (unsigned)(ks * 128 + code);
#pragma unroll
        for (int mask = 1; mask <= 32; mask <<= 1) {
            unsigned long long o = __shfl_xor(p, mask);
            p = o < p ? o : p;
        }
        if ((tid & 63) == 0) atomicMin(&slot[e], p);
    }
}

__global__ void vq_write(const int* __restrict__ cnt, const int* __restrict__ list,
                         const unsigned long long* __restrict__ slot,
                         int* __restrict__ out) {
    int t = blockIdx.x * 256 + threadIdx.x;
    if (t < *cnt) out[list[t]] = (int)(slot[t] & 0xFFFFFFFFull);
}

// ================= fallback 2: validated round-1 fp32 path =================
#define BM 128
#define BN 128
#define PAD 68

__global__ void vq_norms_fb(const float4* __restrict__ cb, float* __restrict__ c2) {
    int t = blockIdx.x * 256 + threadIdx.x;
    int r = t >> 2, p = t & 3;
    float s = 0.f;
#pragma unroll
    for (int i = 0; i < 4; ++i) {
        float4 v = cb[r * 16 + p * 4 + i];
        s += v.x * v.x + v.y * v.y + v.z * v.z + v.w * v.w;
    }
    s += __shfl_xor(s, 1);
    s += __shfl_xor(s, 2);
    if (p == 0) c2[r] = s;
}

__global__ __launch_bounds__(256) void vq_fp32(
    const float4* __restrict__ lat, const float4* __restrict__ cb,
    const float* __restrict__ c2, int ktPer,
    int* __restrict__ outIdx, float* __restrict__ partS, int* __restrict__ partI,
    int writePartial) {
    __shared__ float As[BM][PAD];
    __shared__ float Bsf[BN][PAD];
    __shared__ float c2s[BN];
    const int tid = threadIdx.x;
    const int tx = tid & 15;
    const int ty = tid >> 4;
    const int nBase = blockIdx.x * BM;
    const int kt0 = blockIdx.y * ktPer;
    const int ktN = kt0 + ktPer;
#pragma unroll
    for (int r = 0; r < 8; ++r) {
        int f = tid + 256 * r;
        int mm = f >> 4, d4 = f & 15;
        float4 v = lat[(size_t)(nBase + mm) * 16 + d4];
        *(float4*)&As[mm][d4 * 4] = v;
    }
    float best[8]; int bidx[8];
#pragma unroll
    for (int ii = 0; ii < 8; ++ii) { best[ii] = 3e38f; bidx[ii] = 0; }
    for (int kt = kt0; kt < ktN; ++kt) {
        const int kbase = kt * BN;
        __syncthreads();
#pragma unroll
        for (int r = 0; r < 8; ++r) {
            int f = tid + 256 * r;
            int k = f >> 4, d4 = f & 15;
            float4 v = cb[(size_t)(kbase + k) * 16 + d4];
            *(float4*)&Bsf[k][d4 * 4] = v;
        }
        if (tid < BN) c2s[tid] = c2[kbase + tid];
        __syncthreads();
        float acc[8][8];
#pragma unroll
        for (int ii = 0; ii < 8; ++ii)
#pragma unroll
            for (int jj = 0; jj < 8; ++jj) acc[ii][jj] = 0.f;
#pragma unroll 4
        for (int d4 = 0; d4 < 16; ++d4) {
            float4 a[8], b[8];
#pragma unroll
            for (int ii = 0; ii < 8; ++ii) a[ii] = *(const float4*)&As[tx + 16 * ii][d4 * 4];
#pragma unroll
            for (int jj = 0; jj < 8; ++jj) b[jj] = *(const float4*)&Bsf[ty + 16 * jj][d4 * 4];
#pragma unroll
            for (int ii = 0; ii < 8; ++ii)
#pragma unroll
                for (int jj = 0; jj < 8; ++jj)
                    acc[ii][jj] += a[ii].x * b[jj].x + a[ii].y * b[jj].y
                                 + a[ii].z * b[jj].z + a[ii].w * b[jj].w;
        }
#pragma unroll
        for (int jj = 0; jj < 8; ++jj) {
            int k = kbase + ty + 16 * jj;
            float cc = c2s[ty + 16 * jj];
#pragma unroll
            for (int ii = 0; ii < 8; ++ii) {
                float s = cc - 2.f * acc[ii][jj];
                if (s < best[ii]) { best[ii] = s; bidx[ii] = k; }
            }
        }
    }
    __syncthreads();
    float* redS = &As[0][0];
    int*   redI = (int*)&Bsf[0][0];
#pragma unroll
    for (int ii = 0; ii < 8; ++ii) {
        int mm = tx + 16 * ii;
        redS[ty * BM + mm] = best[ii];
        redI[ty * BM + mm] = bidx[ii];
    }
    __syncthreads();
    if (tid < BM) {
        int mm = tid;
        float bs = redS[mm]; int bi = redI[mm];
#pragma unroll
        for (int t = 1; t < 16; ++t) {
            float s = redS[t * BM + mm]; int i = redI[t * BM + mm];
            if (s < bs || (s == bs && i < bi)) { bs = s; bi = i; }
        }
        int n = nBase + mm;
        if (writePartial) { partS[blockIdx.y * N_TOTAL + n] = bs; partI[blockIdx.y * N_TOTAL + n] = bi; }
        else outIdx[n] = bi;
    }
}

__global__ void vq_merge_fb(const float* __restrict__ partS, const int* __restrict__ partI,
                            int* __restrict__ out) {
    int n = blockIdx.x * 256 + threadIdx.x;
    float s0 = partS[n], s1 = partS[N_TOTAL + n];
    int   i0 = partI[n], i1 = partI[N_TOTAL + n];
    out[n] = (s1 < s0) ? i1 : i0;
}

extern "C" void kernel_launch(void* const* d_in, const int* in_sizes, int n_in,
                              void* d_out, int out_size, void* d_ws, size_t ws_size,
                              hipStream_t stream) {
    const float4* lat = (const float4*)d_in[0];
    const float4* cb  = (const float4*)d_in[1];
    int* out = (int*)d_out;
    char* ws = (char*)d_ws;

    if (ws_size >= WS_NEED) {
        float* c2   = (float*)(ws + O_C2);
        uint4* cbSw = (uint4*)(ws + O_CBSW);
        float* pS1  = (float*)(ws + O_PS1);
        float* pS2  = (float*)(ws + O_PS2);
        int*   pI1  = (int*)(ws + O_PI1);
        int*   cntbar = (int*)(ws + O_CNT);
        int*   list = (int*)(ws + O_LIST);
        unsigned long long* slot = (unsigned long long*)(ws + O_SLOT);

        hipMemsetAsync(cntbar, 0, 32, stream);   // cnt + 4 barrier counters
        vq_fused2<<<GRID_F, 256, 0, stream>>>(lat, cb, out, c2, cbSw,
                                              pS1, pS2, pI1, cntbar, list, slot);
    } else {
        float* c2 = (float*)ws;
        vq_norms_fb<<<128, 256, 0, stream>>>(cb, c2);
        const size_t needSplit = 32768u + 2u * N_TOTAL * 4u + 2u * N_TOTAL * 4u + 64u;
        if (ws_size >= needSplit) {
            float* partS = (float*)(ws + 32768);
            int*   partI = (int*)(ws + 32768 + 2 * N_TOTAL * 4);
            dim3 grid(N_TOTAL / BM, 2);
            vq_fp32<<<grid, 256, 0, stream>>>(lat, cb, c2, (K_CODES / BN) / 2, out, partS, partI, 1);
            vq_merge_fb<<<N_TOTAL / 256, 256, 0, stream>>>(partS, partI, out);
        } else {
            dim3 grid(N_TOTAL / BM, 1);
            vq_fp32<<<grid, 256, 0, stream>>>(lat, cb, c2, K_CODES / BN, out, nullptr, nullptr, 0);
        }
    }
}

// Round 11
// 427.501 us; speedup vs baseline: 1.8885x; 1.8885x over previous
//
#include <hip/hip_runtime.h>
#include <stdint.h>

// VQ-VAE nearest-codebook index: N=32768 queries, D=64, K=8192 codes.
// R11: 3 dispatches (harness charges ~22us per dispatch; R9's 5-dispatch
// residue was 139us, R7/R10 fused-residue ~25us):
//   1. vq_prep16 (grid 256): codebook hi/lo bf16 split + norms + zero cnt/bars
//   2. vq_mfma16 (grid 1024): R9-proven 16x16x32 bf16x3 + s2 tracking,
//      now launch_bounds(256,4) -- natural ~100 VGPR <= cap 128 (R9: 84 arch
//      at cap 170, no spill). NEVER cap below natural (R4/R8/R10: 0.5-1.2GB
//      scratch WRITE_SIZE when capped under the fat kernel's footprint).
//   3. vq_post (grid 256, tiny VGPR/33.5KB LDS -> co-residency trivially
//      guaranteed): merge 4 partitions + flag | grid-bar | k-tiled exact fp32
//      (codebook slice staged once per block, CBP=129 pad) | grid-bar | write.
// MFMA body must NOT live inside a bounds-forced co-resident kernel (R7: grid
// starvation; R10: cap spill). Fallback: validated fp32 path if ws too small.

#define N_TOTAL 32768
#define K_CODES 8192
#define EPS_GAP 0.015f
#define NPART   4
#define GRID_P  256
#define CBP     129

typedef __attribute__((ext_vector_type(4))) float  floatx4;
typedef __attribute__((ext_vector_type(8))) __bf16 bf16x8;

// ---- workspace layout (bytes) ----
#define O_C2    0u          // 8192 f32
#define O_CBSW  32768u      // [512 tile16][hi/lo][h][g][code16] = 2 MB
#define O_PS1   2129920u    // 4*32768 f32
#define O_PS2   2654208u    // 4*32768 f32
#define O_PI1   3178496u    // 4*32768 i32
#define O_CNT   3702784u    // cnt @ +0, barrier counters @ +16..+31
#define O_LIST  3703040u    // 32768 int
#define O_SLOT  3834112u    // 32768 u64
#define WS_NEED 4096256u

#if defined(__has_builtin)
#if __has_builtin(__builtin_amdgcn_fmed3f)
#define MED3(a, b, c) __builtin_amdgcn_fmed3f((a), (b), (c))
#endif
#endif
#ifndef MED3
#define MED3(a, b, c) fminf((c), fmaxf((a), (b)))
#endif

__device__ __forceinline__ unsigned int fkey(float s) {
    unsigned int u = __float_as_uint(s);
    return (u & 0x80000000u) ? ~u : (u | 0x80000000u);
}

__device__ __forceinline__ void load_lds16(const void* g, void* l) {
    __builtin_amdgcn_global_load_lds(
        (const __attribute__((address_space(1))) unsigned int*)g,
        (__attribute__((address_space(3))) unsigned int*)l, 16, 0, 0);
}

// single-use device-scope grid barrier; counter pre-zeroed by vq_prep16.
__device__ __forceinline__ void grid_bar(int* bar, int target) {
    __syncthreads();
    if (threadIdx.x == 0) {
        __threadfence();
        atomicAdd(bar, 1);
        while (__hip_atomic_load(bar, __ATOMIC_RELAXED, __HIP_MEMORY_SCOPE_AGENT) < target)
            __builtin_amdgcn_s_sleep(1);
        __threadfence();
    }
    __syncthreads();
}

// ---- K1: codebook -> hi/lo bf16 16x16x32-B-fragment layout + norms + zero ----
__global__ __launch_bounds__(256) void vq_prep16(
    const float4* __restrict__ cb, uint4* __restrict__ cbSw,
    float* __restrict__ c2, int* __restrict__ cntbar) {
    const int t = blockIdx.x * 256 + threadIdx.x;   // 65536 items = code*8+sub
    if (t < 8) cntbar[t] = 0;                        // cnt + barrier counters
    const int code = t >> 3, sub = t & 7, h = sub >> 2, g = sub & 3;
    float4 f0 = cb[(size_t)code * 16 + h * 8 + g * 2];
    float4 f1 = cb[(size_t)code * 16 + h * 8 + g * 2 + 1];
    float x[8] = {f0.x, f0.y, f0.z, f0.w, f1.x, f1.y, f1.z, f1.w};
    bf16x8 hv, lv;
    float ss = 0.f;
#pragma unroll
    for (int i = 0; i < 8; ++i) {
        float v  = x[i];
        __bf16 hb = (__bf16)v;           // RNE
        hv[i] = hb;
        lv[i] = (__bf16)(v - (float)hb);
        ss += v * v;
    }
    const int base = (code >> 4) * 256 + h * 64 + g * 16 + (code & 15);
    cbSw[base]       = __builtin_bit_cast(uint4, hv);
    cbSw[base + 128] = __builtin_bit_cast(uint4, lv);
    ss += __shfl_xor(ss, 1);
    ss += __shfl_xor(ss, 2);
    ss += __shfl_xor(ss, 4);
    if (sub == 0) c2[code] = ss;
}

// ---- K2: phase A, 128 queries x 2048 codes per block (split-K=4) ----
__global__ __launch_bounds__(256, 4) void vq_mfma16(
    const float4* __restrict__ lat, const uint4* __restrict__ cbSw,
    const float* __restrict__ c2,
    float* __restrict__ pS1, float* __restrict__ pS2, int* __restrict__ pI1) {
    __shared__ uint4 Bs[2048];   // 32 KB: 8 tiles x 256 uint4
    const int tid = threadIdx.x;
    const int wr = tid >> 6, lane = tid & 63;
    const int lm = lane & 15, lg = lane >> 4;
    const int qBaseW = blockIdx.x * 128 + wr * 32;

    // A fragments, split in-kernel: A[m=lane&15][k=(lane>>4)*8+j], halves h=0/1.
    bf16x8 aH[2][2], aL[2][2];
#pragma unroll
    for (int qt = 0; qt < 2; ++qt) {
        const int q = qBaseW + qt * 16 + lm;
#pragma unroll
        for (int h = 0; h < 2; ++h) {
            float4 v0 = lat[(size_t)q * 16 + h * 8 + lg * 2];
            float4 v1 = lat[(size_t)q * 16 + h * 8 + lg * 2 + 1];
            float x[8] = {v0.x, v0.y, v0.z, v0.w, v1.x, v1.y, v1.z, v1.w};
#pragma unroll
            for (int j = 0; j < 8; ++j) {
                float v  = x[j];
                __bf16 hb = (__bf16)v;
                aH[qt][h][j] = hb;
                aL[qt][h][j] = (__bf16)(v - (float)hb);
            }
        }
    }

    float s1[2][4], s2[2][4]; int i1[2][4];
#pragma unroll
    for (int qt = 0; qt < 2; ++qt)
#pragma unroll
        for (int r = 0; r < 4; ++r) { s1[qt][r] = 3e38f; s2[qt][r] = 3e38f; i1[qt][r] = 0; }

    const int kBase = blockIdx.y * 2048;
    const size_t uBase = (size_t)blockIdx.y * 32768;

    for (int stage = 0; stage < 16; ++stage) {
        __syncthreads();
#pragma unroll
        for (int i = 0; i < 8; ++i)
            load_lds16(&cbSw[uBase + stage * 2048 + wr * 64 + 256 * i + lane],
                       &Bs[wr * 64 + 256 * i]);
        __syncthreads();

#pragma unroll
        for (int t = 0; t < 8; ++t) {
            const int b = t * 256;
            bf16x8 bH0 = __builtin_bit_cast(bf16x8, Bs[b + lane]);
            bf16x8 bH1 = __builtin_bit_cast(bf16x8, Bs[b + 64 + lane]);
            bf16x8 bL0 = __builtin_bit_cast(bf16x8, Bs[b + 128 + lane]);
            bf16x8 bL1 = __builtin_bit_cast(bf16x8, Bs[b + 192 + lane]);
            const int col = kBase + stage * 128 + t * 16 + lm;
            const float cc = c2[col];
#pragma unroll
            for (int qt = 0; qt < 2; ++qt) {
                floatx4 acc = {0.f, 0.f, 0.f, 0.f};
                acc = __builtin_amdgcn_mfma_f32_16x16x32_bf16(aH[qt][0], bH0, acc, 0, 0, 0);
                acc = __builtin_amdgcn_mfma_f32_16x16x32_bf16(aH[qt][1], bH1, acc, 0, 0, 0);
                acc = __builtin_amdgcn_mfma_f32_16x16x32_bf16(aL[qt][0], bH0, acc, 0, 0, 0);
                acc = __builtin_amdgcn_mfma_f32_16x16x32_bf16(aL[qt][1], bH1, acc, 0, 0, 0);
                acc = __builtin_amdgcn_mfma_f32_16x16x32_bf16(aH[qt][0], bL0, acc, 0, 0, 0);
                acc = __builtin_amdgcn_mfma_f32_16x16x32_bf16(aH[qt][1], bL1, acc, 0, 0, 0);
#pragma unroll
                for (int r = 0; r < 4; ++r) {
                    float s = fmaf(-2.f, acc[r], cc);
                    s2[qt][r] = MED3(s, s1[qt][r], s2[qt][r]);   // min(s2,max(s,s1))
                    bool lt = s < s1[qt][r];
                    i1[qt][r] = lt ? col : i1[qt][r];
                    s1[qt][r] = lt ? s : s1[qt][r];
                }
            }
        }
    }

#pragma unroll
    for (int mask = 1; mask <= 8; mask <<= 1) {
#pragma unroll
        for (int qt = 0; qt < 2; ++qt)
#pragma unroll
            for (int r = 0; r < 4; ++r) {
                float o1 = __shfl_xor(s1[qt][r], mask);
                float o2 = __shfl_xor(s2[qt][r], mask);
                int   oi = __shfl_xor(i1[qt][r], mask);
                float n2 = fminf(fminf(s2[qt][r], o2), fmaxf(s1[qt][r], o1));
                bool take = (o1 < s1[qt][r]) || (o1 == s1[qt][r] && oi < i1[qt][r]);
                s1[qt][r] = take ? o1 : s1[qt][r];
                i1[qt][r] = take ? oi : i1[qt][r];
                s2[qt][r] = n2;
            }
    }

    if (lm == 0) {
        const int o0 = blockIdx.y * N_TOTAL;
#pragma unroll
        for (int qt = 0; qt < 2; ++qt)
#pragma unroll
            for (int r = 0; r < 4; ++r) {
                int q = qBaseW + qt * 16 + lg * 4 + r;   // C/D row = lg*4+r
                pS1[o0 + q] = s1[qt][r];
                pS2[o0 + q] = s2[qt][r];
                pI1[o0 + q] = i1[qt][r];
            }
    }
}

// ---- K3: merge + flag | bar | exact fp32 k-tiled | bar | write (grid 256) ----
__global__ __launch_bounds__(256) void vq_post(
    const float4* __restrict__ lat, const float4* __restrict__ cb,
    const float* __restrict__ c2, int* __restrict__ out,
    const float* __restrict__ pS1, const float* __restrict__ pS2,
    const int* __restrict__ pI1, int* __restrict__ cntbar,
    int* __restrict__ list, unsigned long long* __restrict__ slot) {
    __shared__ float CbT[64 * CBP];
    __shared__ float c2s[128];
    const int tid = threadIdx.x;
    const int bid = blockIdx.x;
    int* cnt  = cntbar;
    int* bars = cntbar + 4;

    // phase 1: merge 4 partitions, write indices, flag near-ties (blocks 0..127)
    if (bid < 128) {
        int q = bid * 256 + tid;
        float g1 = 3e38f, g2 = 3e38f;
        int   gi = 0x7FFFFFFF;
#pragma unroll
        for (int p = 0; p < NPART; ++p) {
            float s1p = pS1[p * N_TOTAL + q];
            float s2p = pS2[p * N_TOTAL + q];
            int   i1p = pI1[p * N_TOTAL + q];
            bool take = (s1p < g1) || (s1p == g1 && i1p < gi);
            g2 = fminf(g2, fminf(s2p, take ? g1 : s1p));
            if (take) { g1 = s1p; gi = i1p; }
        }
        out[q] = gi;
        if (g2 - g1 < EPS_GAP) {
            int e = atomicAdd(cnt, 1);
            list[e] = q;
            slot[e] = 0xFFFFFFFFFFFFFFFFull;
        }
    }
    grid_bar(&bars[0], GRID_P);

    // phase 2: exact fp32 for flagged queries; 64 code-slices x 4 e-groups
    {
        const int n = *cnt;
        if (n > 0) {
            const int ks = bid >> 2, egrp = bid & 3;
            for (int i = tid; i < 2048; i += 256) {
                int code = i >> 4, d4 = i & 15;
                float4 v = cb[(size_t)(ks * 128 + code) * 16 + d4];
                CbT[(d4 * 4 + 0) * CBP + code] = v.x;
                CbT[(d4 * 4 + 1) * CBP + code] = v.y;
                CbT[(d4 * 4 + 2) * CBP + code] = v.z;
                CbT[(d4 * 4 + 3) * CBP + code] = v.w;
            }
            if (tid < 128) c2s[tid] = c2[ks * 128 + tid];
            __syncthreads();

            const int code = tid >> 1, dh = tid & 1;   // 2 lanes/code: D-halves
            for (int e = egrp; e < n; e += 4) {
                const int qq = list[e];
                const float4* qp = lat + (size_t)qq * 16 + dh * 8;
                float dot = 0.f;
#pragma unroll
                for (int j = 0; j < 8; ++j) {
                    float4 qv = qp[j];
                    dot += qv.x * CbT[(dh * 32 + j * 4 + 0) * CBP + code]
                         + qv.y * CbT[(dh * 32 + j * 4 + 1) * CBP + code]
                         + qv.z * CbT[(dh * 32 + j * 4 + 2) * CBP + code]
                         + qv.w * CbT[(dh * 32 + j * 4 + 3) * CBP + code];
                }
                dot += __shfl_xor(dot, 1);
                float s = c2s[code] - 2.f * dot;
                unsigned long long p =
                    ((unsigned long long)fkey(s) << 32) | (unsigned)(ks * 128 + code);
#pragma unroll
                for (int mask = 1; mask <= 32; mask <<= 1) {
                    unsigned long long o = __shfl_xor(p, mask);
                    p = o < p ? o : p;
                }
                if ((tid & 63) == 0) atomicMin(&slot[e], p);
            }
        }
    }
    grid_bar(&bars[1], GRID_P);

    // phase 3: write back flagged (blocks 0..127)
    if (bid < 128) {
        int t = bid * 256 + tid;
        if (t < *cnt) out[list[t]] = (int)(slot[t] & 0xFFFFFFFFull);
    }
}

// ================= fallback: validated round-1 fp32 path =================
#define BM 128
#define BN 128
#define PAD 68

__global__ void vq_norms_fb(const float4* __restrict__ cb, float* __restrict__ c2) {
    int t = blockIdx.x * 256 + threadIdx.x;
    int r = t >> 2, p = t & 3;
    float s = 0.f;
#pragma unroll
    for (int i = 0; i < 4; ++i) {
        float4 v = cb[r * 16 + p * 4 + i];
        s += v.x * v.x + v.y * v.y + v.z * v.z + v.w * v.w;
    }
    s += __shfl_xor(s, 1);
    s += __shfl_xor(s, 2);
    if (p == 0) c2[r] = s;
}

__global__ __launch_bounds__(256) void vq_fp32(
    const float4* __restrict__ lat, const float4* __restrict__ cb,
    const float* __restrict__ c2, int ktPer,
    int* __restrict__ outIdx, float* __restrict__ partS, int* __restrict__ partI,
    int writePartial) {
    __shared__ float As[BM][PAD];
    __shared__ float Bsf[BN][PAD];
    __shared__ float c2s[BN];
    const int tid = threadIdx.x;
    const int tx = tid & 15;
    const int ty = tid >> 4;
    const int nBase = blockIdx.x * BM;
    const int kt0 = blockIdx.y * ktPer;
    const int ktN = kt0 + ktPer;
#pragma unroll
    for (int r = 0; r < 8; ++r) {
        int f = tid + 256 * r;
        int mm = f >> 4, d4 = f & 15;
        float4 v = lat[(size_t)(nBase + mm) * 16 + d4];
        *(float4*)&As[mm][d4 * 4] = v;
    }
    float best[8]; int bidx[8];
#pragma unroll
    for (int ii = 0; ii < 8; ++ii) { best[ii] = 3e38f; bidx[ii] = 0; }
    for (int kt = kt0; kt < ktN; ++kt) {
        const int kbase = kt * BN;
        __syncthreads();
#pragma unroll
        for (int r = 0; r < 8; ++r) {
            int f = tid + 256 * r;
            int k = f >> 4, d4 = f & 15;
            float4 v = cb[(size_t)(kbase + k) * 16 + d4];
            *(float4*)&Bsf[k][d4 * 4] = v;
        }
        if (tid < BN) c2s[tid] = c2[kbase + tid];
        __syncthreads();
        float acc[8][8];
#pragma unroll
        for (int ii = 0; ii < 8; ++ii)
#pragma unroll
            for (int jj = 0; jj < 8; ++jj) acc[ii][jj] = 0.f;
#pragma unroll 4
        for (int d4 = 0; d4 < 16; ++d4) {
            float4 a[8], b[8];
#pragma unroll
            for (int ii = 0; ii < 8; ++ii) a[ii] = *(const float4*)&As[tx + 16 * ii][d4 * 4];
#pragma unroll
            for (int jj = 0; jj < 8; ++jj) b[jj] = *(const float4*)&Bsf[ty + 16 * jj][d4 * 4];
#pragma unroll
            for (int ii = 0; ii < 8; ++ii)
#pragma unroll
                for (int jj = 0; jj < 8; ++jj)
                    acc[ii][jj] += a[ii].x * b[jj].x + a[ii].y * b[jj].y
                                 + a[ii].z * b[jj].z + a[ii].w * b[jj].w;
        }
#pragma unroll
        for (int jj = 0; jj < 8; ++jj) {
            int k = kbase + ty + 16 * jj;
            float cc = c2s[ty + 16 * jj];
#pragma unroll
            for (int ii = 0; ii < 8; ++ii) {
                float s = cc - 2.f * acc[ii][jj];
                if (s < best[ii]) { best[ii] = s; bidx[ii] = k; }
            }
        }
    }
    __syncthreads();
    float* redS = &As[0][0];
    int*   redI = (int*)&Bsf[0][0];
#pragma unroll
    for (int ii = 0; ii < 8; ++ii) {
        int mm = tx + 16 * ii;
        redS[ty * BM + mm] = best[ii];
        redI[ty * BM + mm] = bidx[ii];
    }
    __syncthreads();
    if (tid < BM) {
        int mm = tid;
        float bs = redS[mm]; int bi = redI[mm];
#pragma unroll
        for (int t = 1; t < 16; ++t) {
            float s = redS[t * BM + mm]; int i = redI[t * BM + mm];
            if (s < bs || (s == bs && i < bi)) { bs = s; bi = i; }
        }
        int n = nBase + mm;
        if (writePartial) { partS[blockIdx.y * N_TOTAL + n] = bs; partI[blockIdx.y * N_TOTAL + n] = bi; }
        else outIdx[n] = bi;
    }
}

__global__ void vq_merge_fb(const float* __restrict__ partS, const int* __restrict__ partI,
                            int* __restrict__ out) {
    int n = blockIdx.x * 256 + threadIdx.x;
    float s0 = partS[n], s1 = partS[N_TOTAL + n];
    int   i0 = partI[n], i1 = partI[N_TOTAL + n];
    out[n] = (s1 < s0) ? i1 : i0;
}

extern "C" void kernel_launch(void* const* d_in, const int* in_sizes, int n_in,
                              void* d_out, int out_size, void* d_ws, size_t ws_size,
                              hipStream_t stream) {
    const float4* lat = (const float4*)d_in[0];
    const float4* cb  = (const float4*)d_in[1];
    int* out = (int*)d_out;
    char* ws = (char*)d_ws;

    if (ws_size >= WS_NEED) {
        float* c2   = (float*)(ws + O_C2);
        uint4* cbSw = (uint4*)(ws + O_CBSW);
        float* pS1  = (float*)(ws + O_PS1);
        float* pS2  = (float*)(ws + O_PS2);
        int*   pI1  = (int*)(ws + O_PI1);
        int*   cntbar = (int*)(ws + O_CNT);
        int*   list = (int*)(ws + O_LIST);
        unsigned long long* slot = (unsigned long long*)(ws + O_SLOT);

        vq_prep16<<<256, 256, 0, stream>>>(cb, cbSw, c2, cntbar);
        vq_mfma16<<<dim3(256, NPART), 256, 0, stream>>>(lat, cbSw, c2, pS1, pS2, pI1);
        vq_post<<<GRID_P, 256, 0, stream>>>(lat, cb, c2, out, pS1, pS2, pI1,
                                            cntbar, list, slot);
    } else {
        float* c2 = (float*)ws;
        vq_norms_fb<<<128, 256, 0, stream>>>(cb, c2);
        const size_t needSplit = 32768u + 2u * N_TOTAL * 4u + 2u * N_TOTAL * 4u + 64u;
        if (ws_size >= needSplit) {
            float* partS = (float*)(ws + 32768);
            int*   partI = (int*)(ws + 32768 + 2 * N_TOTAL * 4);
            dim3 grid(N_TOTAL / BM, 2);
            vq_fp32<<<grid, 256, 0, stream>>>(lat, cb, c2, (K_CODES / BN) / 2, out, partS, partI, 1);
            vq_merge_fb<<<N_TOTAL / 256, 256, 0, stream>>>(partS, partI, out);
        } else {
            dim3 grid(N_TOTAL / BM, 1);
            vq_fp32<<<grid, 256, 0, stream>>>(lat, cb, c2, K_CODES / BN, out, nullptr, nullptr, 0);
        }
    }
}